// Round 2
// baseline (123.527 us; speedup 1.0000x reference)
//
#include <hip/hip_runtime.h>

typedef __attribute__((ext_vector_type(4))) float f32x4;
typedef __attribute__((ext_vector_type(8))) short bf16x8;
typedef __attribute__((ext_vector_type(4))) unsigned int u32x4;
typedef unsigned short ushort_t;

#define B_ROWS 65536
#define L_DIM  256
#define H_IN_D 300
#define H_PAD  320
#define BM     64
#define LDH    328   // hbuf row stride in ushorts (320 + 8 pad)
#define LDV    264   // vbuf row stride in ushorts (256 + 8 pad)
#define NTH    256

__device__ __forceinline__ ushort_t f2bf(float f) {
  unsigned u = __builtin_bit_cast(unsigned, f);
  unsigned r = u + 0x7fffu + ((u >> 16) & 1u);   // RNE, no NaN in data
  return (ushort_t)(r >> 16);
}
__device__ __forceinline__ float bflo(unsigned u) { return __builtin_bit_cast(float, u << 16); }
__device__ __forceinline__ float bfhi(unsigned u) { return __builtin_bit_cast(float, u & 0xffff0000u); }

// ---------------- weight pre-conversion (once per launch, ~µs) ----------------
__global__ void cvt_w(const float* __restrict__ W0, const float* __restrict__ Ws,
                      ushort_t* __restrict__ W0b, ushort_t* __restrict__ Wsb) {
  int i = blockIdx.x * blockDim.x + threadIdx.x;
  int stride = gridDim.x * blockDim.x;
  // W0 [256][300] f32 -> [256][320] bf16 zero-padded
  for (int t = i; t < 256 * H_PAD; t += stride) {
    int n = t / H_PAD, k = t - n * H_PAD;
    W0b[t] = (k < H_IN_D) ? f2bf(W0[n * H_IN_D + k]) : (ushort_t)0;
  }
  // Ws [3][256][256]
  for (int t = i; t < 3 * 256 * 256; t += stride) Wsb[t] = f2bf(Ws[t]);
}

// ---------------- fused flow kernel ----------------
// Per k-step GEMM: A frag = lane reads A[mt*16 + r][k0 + g*8 .. +7] (LDS bf16)
//                  B frag = lane reads W[c0+nt*16+r][k0 + g*8 .. +7] (global bf16)
// C/D layout (m89-verified): row = g*4 + reg, col = r  within each 16x16 tile.
template<int KSTEPS, int LDA>
__device__ __forceinline__ void gemm_stage(
    const ushort_t* __restrict__ Alds,
    const ushort_t* __restrict__ Bg, int ldb,
    const float* __restrict__ bias,
    ushort_t* __restrict__ Olds,
    int wave, int r, int g)
{
  f32x4 acc[4][4];
#pragma unroll
  for (int mt = 0; mt < 4; ++mt)
#pragma unroll
    for (int nt = 0; nt < 4; ++nt) { acc[mt][nt][0] = 0.f; acc[mt][nt][1] = 0.f; acc[mt][nt][2] = 0.f; acc[mt][nt][3] = 0.f; }

  const int c0 = wave * 64;
  const ushort_t* Abase = Alds + r * LDA + g * 8;
  const ushort_t* Bb0 = Bg + (c0 + 0 * 16 + r) * ldb + g * 8;
  const ushort_t* Bb1 = Bg + (c0 + 1 * 16 + r) * ldb + g * 8;
  const ushort_t* Bb2 = Bg + (c0 + 2 * 16 + r) * ldb + g * 8;
  const ushort_t* Bb3 = Bg + (c0 + 3 * 16 + r) * ldb + g * 8;

#pragma unroll
  for (int ks = 0; ks < KSTEPS; ++ks) {
    bf16x8 b0 = *(const bf16x8*)(Bb0 + ks * 32);
    bf16x8 b1 = *(const bf16x8*)(Bb1 + ks * 32);
    bf16x8 b2 = *(const bf16x8*)(Bb2 + ks * 32);
    bf16x8 b3 = *(const bf16x8*)(Bb3 + ks * 32);
    bf16x8 a[4];
#pragma unroll
    for (int mt = 0; mt < 4; ++mt) a[mt] = *(const bf16x8*)(Abase + mt * 16 * LDA + ks * 32);
#pragma unroll
    for (int mt = 0; mt < 4; ++mt) {
      acc[mt][0] = __builtin_amdgcn_mfma_f32_16x16x32_bf16(a[mt], b0, acc[mt][0], 0, 0, 0);
      acc[mt][1] = __builtin_amdgcn_mfma_f32_16x16x32_bf16(a[mt], b1, acc[mt][1], 0, 0, 0);
      acc[mt][2] = __builtin_amdgcn_mfma_f32_16x16x32_bf16(a[mt], b2, acc[mt][2], 0, 0, 0);
      acc[mt][3] = __builtin_amdgcn_mfma_f32_16x16x32_bf16(a[mt], b3, acc[mt][3], 0, 0, 0);
    }
  }

  // epilogue: +bias, cvt bf16, write v tile to LDS
#pragma unroll
  for (int nt = 0; nt < 4; ++nt) {
    float bv = bias[c0 + nt * 16 + r];
#pragma unroll
    for (int mt = 0; mt < 4; ++mt) {
#pragma unroll
      for (int j = 0; j < 4; ++j) {
        float val = acc[mt][nt][j] + bv;
        Olds[(mt * 16 + g * 4 + j) * LDV + c0 + nt * 16 + r] = f2bf(val);
      }
    }
  }
}

// Householder update: z -= 2 v (v.z)/(v.v), v from LDS (bf16), z in registers.
// Row = wave*16 + r; lane owns cols g*64 .. g*64+63. Reduce across the 4 lanes
// sharing a row via shfl_xor(16), shfl_xor(32).
__device__ __forceinline__ void dot_update(const ushort_t* __restrict__ V,
                                           int wave, int r, int g, float (&zr)[64])
{
  const ushort_t* vp = V + (wave * 16 + r) * LDV + g * 64;
  float vz = 0.f, vv = 0.f;
#pragma unroll
  for (int jb = 0; jb < 8; ++jb) {
    u32x4 q = *(const u32x4*)(vp + jb * 8);
#pragma unroll
    for (int w = 0; w < 4; ++w) {
      unsigned u = q[w];
      float f0 = bflo(u), f1 = bfhi(u);
      int i = jb * 8 + w * 2;
      vz = fmaf(f0, zr[i], vz);     vv = fmaf(f0, f0, vv);
      vz = fmaf(f1, zr[i + 1], vz); vv = fmaf(f1, f1, vv);
    }
  }
  vz += __shfl_xor(vz, 16); vz += __shfl_xor(vz, 32);
  vv += __shfl_xor(vv, 16); vv += __shfl_xor(vv, 32);
  float a = 2.f * vz / vv;
#pragma unroll
  for (int jb = 0; jb < 8; ++jb) {
    u32x4 q = *(const u32x4*)(vp + jb * 8);
#pragma unroll
    for (int w = 0; w < 4; ++w) {
      unsigned u = q[w];
      int i = jb * 8 + w * 2;
      zr[i]     = fmaf(-a, bflo(u), zr[i]);
      zr[i + 1] = fmaf(-a, bfhi(u), zr[i + 1]);
    }
  }
}

__global__ __launch_bounds__(NTH, 2) void flow_fused(
    const float* __restrict__ z, const float* __restrict__ h,
    const ushort_t* __restrict__ W0b, const float* __restrict__ b0,
    const ushort_t* __restrict__ Wsb, const float* __restrict__ bs,
    float* __restrict__ out)
{
  // LDS: vb0 [64][264]bf16 (33792B), vb1 [64][264] aliased with hbuf [64][328] (41984B)
  __shared__ __align__(16) ushort_t smem[BM * LDV + BM * LDH];  // 75776 B
  ushort_t* vb0 = smem;
  ushort_t* vb1 = smem + BM * LDV;
  ushort_t* hbuf = vb1;  // alias: hbuf dead before vb1 is first written (stage-2 epilogue)

  const int tid  = threadIdx.x;
  const int wave = tid >> 6;
  const int lane = tid & 63;
  const int r    = lane & 15;
  const int g    = lane >> 4;
  const int row0 = blockIdx.x * BM;

  // ---- load h tile -> hbuf (bf16, K padded 300->320 with zeros) ----
  for (int row = wave; row < BM; row += 4) {
    const float* hrow = h + (row0 + row) * H_IN_D;
#pragma unroll
    for (int cc = 0; cc < 5; ++cc) {
      int c = lane + cc * 64;
      float v = (c < H_IN_D) ? hrow[c] : 0.f;
      hbuf[row * LDH + c] = f2bf(v);
    }
  }

  // ---- load z tile into registers ----
  float zr[64];
  const int zrow = wave * 16 + r;
  {
    const float* zp = z + (row0 + zrow) * L_DIM + g * 64;
#pragma unroll
    for (int j = 0; j < 16; ++j) {
      f32x4 v = *(const f32x4*)(zp + j * 4);
      zr[j * 4 + 0] = v[0]; zr[j * 4 + 1] = v[1];
      zr[j * 4 + 2] = v[2]; zr[j * 4 + 3] = v[3];
    }
  }

  __syncthreads();

  // stage 1: v1 = h @ W0^T + b0   (K=320 padded)
  gemm_stage<10, LDH>(hbuf, W0b, H_PAD, b0, vb0, wave, r, g);
  __syncthreads();
  dot_update(vb0, wave, r, g, zr);

  // stages 2..4: v = v @ Ws[s]^T + bs[s]
  for (int s = 0; s < 3; ++s) {
    const ushort_t* src = (s & 1) ? vb1 : vb0;
    ushort_t*       dst = (s & 1) ? vb0 : vb1;
    gemm_stage<8, LDV>(src, Wsb + s * 256 * 256, 256, bs + s * 256, dst, wave, r, g);
    __syncthreads();
    dot_update(dst, wave, r, g, zr);
  }

  // ---- store z ----
  {
    float* op = out + (row0 + zrow) * L_DIM + g * 64;
#pragma unroll
    for (int j = 0; j < 16; ++j) {
      f32x4 v;
      v[0] = zr[j * 4 + 0]; v[1] = zr[j * 4 + 1];
      v[2] = zr[j * 4 + 2]; v[3] = zr[j * 4 + 3];
      *(f32x4*)(op + j * 4) = v;
    }
  }
}

extern "C" void kernel_launch(void* const* d_in, const int* in_sizes, int n_in,
                              void* d_out, int out_size, void* d_ws, size_t ws_size,
                              hipStream_t stream) {
  const float* z  = (const float*)d_in[0];
  const float* h  = (const float*)d_in[1];
  const float* W0 = (const float*)d_in[2];
  const float* b0 = (const float*)d_in[3];
  const float* Ws = (const float*)d_in[4];
  const float* bs = (const float*)d_in[5];
  float* out = (float*)d_out;

  ushort_t* W0b = (ushort_t*)d_ws;            // 256*320 bf16 = 163840 B
  ushort_t* Wsb = W0b + 256 * H_PAD;          // 3*256*256 bf16 = 393216 B

  hipLaunchKernelGGL(cvt_w, dim3(256), dim3(NTH), 0, stream, W0, Ws, W0b, Wsb);
  hipLaunchKernelGGL(flow_fused, dim3(B_ROWS / BM), dim3(NTH), 0, stream,
                     z, h, W0b, b0, Wsb, bs, out);
}